// Round 1
// baseline (896.237 us; speedup 1.0000x reference)
//
#include <hip/hip_runtime.h>

// ---------------------------------------------------------------------------
// DSTGCN fused pipeline, MI355X gfx950.
// Stages: (A) LayerNorm(node_emb + time_emb) -> e (bf16)
//         (X) transpose x -> xT (bf16) for PV B-operand
//         (B) flash attention x_g2 = softmax(e e^T) x   [bf16 MFMA, fp32 acc]
//         (C) out = x*W0 + x_g2*W1 + bias, W_k = node_emb . weights_pool
// ---------------------------------------------------------------------------

using bf16x8 = __attribute__((ext_vector_type(8))) __bf16;
using f32x4  = __attribute__((ext_vector_type(4))) float;

__device__ __forceinline__ unsigned short f2bf_bits(float f) {
    unsigned int u = __float_as_uint(f);
    u += 0x7fffu + ((u >> 16) & 1u);          // RNE
    return (unsigned short)(u >> 16);
}

__device__ __forceinline__ f32x4 mfma_bf16(bf16x8 a, bf16x8 b, f32x4 c) {
    return __builtin_amdgcn_mfma_f32_16x16x32_bf16(a, b, c, 0, 0, 0);
}

// ---------------- Stage A: e = LN(node_emb + time_emb), bf16 out -----------
__global__ __launch_bounds__(256) void k_ln(const float* __restrict__ node_emb,
                                            const float* __restrict__ time_emb,
                                            const float* __restrict__ gamma,
                                            const float* __restrict__ beta,
                                            unsigned short* __restrict__ e_bf) {
    int row  = blockIdx.x * 4 + (threadIdx.x >> 6);   // 0..24575 = bt*4096+n
    int lane = threadIdx.x & 63;                      // d index
    int bt = row >> 12, n = row & 4095;
    float v  = node_emb[(n << 6) | lane] + time_emb[(bt << 6) | lane];
    float s = v, s2 = v * v;
    #pragma unroll
    for (int off = 32; off; off >>= 1) {
        s  += __shfl_xor(s,  off);
        s2 += __shfl_xor(s2, off);
    }
    float mu  = s * 0.015625f;
    float var = s2 * 0.015625f - mu * mu;
    float r   = rsqrtf(var + 1e-12f);
    float o   = (v - mu) * r * gamma[lane] + beta[lane];
    e_bf[(row << 6) | lane] = f2bf_bits(o);
}

// ---------------- Stage X: xT[bt][d][n] = bf16(x[bt][n][d]) ----------------
__global__ __launch_bounds__(256) void k_xt(const float* __restrict__ x,
                                            unsigned short* __restrict__ xT) {
    int idx = blockIdx.x * 256 + threadIdx.x;   // over 6*64*4096
    int bt  = idx >> 18;
    int rem = idx & 262143;
    int d   = rem >> 12;
    int n   = rem & 4095;
    xT[idx] = f2bf_bits(x[(((bt << 12) | n) << 6) | d]);
}

// ---------------- Stage B: flash attention (per-wave 16 q rows) ------------
// Block = 4 waves, 64 q rows. Wave w owns rows [blk*64 + w*16, +16).
// K/V fragments loaded directly from global (L2-resident).
__global__ __launch_bounds__(256) void k_attn(const unsigned short* __restrict__ e_bf,
                                              const unsigned short* __restrict__ xT,
                                              float* __restrict__ xg2) {
    __shared__ __align__(16) unsigned short P_lds[4][16][72];  // per-wave P, padded
    const int bt   = blockIdx.y;
    const int w    = threadIdx.x >> 6;
    const int lane = threadIdx.x & 63;
    const int l16  = lane & 15;
    const int quad = lane >> 4;
    const int qbase = (blockIdx.x << 6) + (w << 4);

    const unsigned short* eb = e_bf + ((size_t)bt << 18);  // bt*4096*64
    const unsigned short* xb = xT   + ((size_t)bt << 18);

    // Q fragments (A-operand): Q[q=l16][d = h*32 + quad*8 + j], resident
    bf16x8 qf0 = *(const bf16x8*)(eb + ((qbase + l16) << 6) + (quad << 3));
    bf16x8 qf1 = *(const bf16x8*)(eb + ((qbase + l16) << 6) + 32 + (quad << 3));

    f32x4 O[4];
    float m_[4], l_[4];
    #pragma unroll
    for (int r = 0; r < 4; ++r) {
        O[r] = f32x4{0.f, 0.f, 0.f, 0.f};
        m_[r] = -1e30f; l_[r] = 0.f;
    }

    for (int kt = 0; kt < 64; ++kt) {
        const int k0 = kt << 6;
        // ---- S = Q K^T (4 subtiles of 16 keys) ----
        f32x4 S[4];
        #pragma unroll
        for (int ct = 0; ct < 4; ++ct) {
            const unsigned short* kr = eb + ((k0 + (ct << 4) + l16) << 6) + (quad << 3);
            bf16x8 kf0 = *(const bf16x8*)(kr);
            bf16x8 kf1 = *(const bf16x8*)(kr + 32);
            f32x4 acc = f32x4{0.f, 0.f, 0.f, 0.f};
            acc = mfma_bf16(qf0, kf0, acc);
            acc = mfma_bf16(qf1, kf1, acc);
            S[ct] = acc;
        }
        // ---- online softmax; rows q = quad*4 + r, cols = ct*16 + l16 ----
        #pragma unroll
        for (int r = 0; r < 4; ++r) {
            float mt = fmaxf(fmaxf(S[0][r], S[1][r]), fmaxf(S[2][r], S[3][r]));
            mt = fmaxf(mt, __shfl_xor(mt, 1));
            mt = fmaxf(mt, __shfl_xor(mt, 2));
            mt = fmaxf(mt, __shfl_xor(mt, 4));
            mt = fmaxf(mt, __shfl_xor(mt, 8));
            float mnew  = fmaxf(m_[r], mt);
            float alpha = __expf(m_[r] - mnew);
            float ls = 0.f;
            #pragma unroll
            for (int ct = 0; ct < 4; ++ct) {
                float p = __expf(S[ct][r] - mnew);
                ls += p;
                P_lds[w][(quad << 2) + r][(ct << 4) + l16] = f2bf_bits(p);
            }
            ls += __shfl_xor(ls, 1);
            ls += __shfl_xor(ls, 2);
            ls += __shfl_xor(ls, 4);
            ls += __shfl_xor(ls, 8);
            l_[r] = l_[r] * alpha + ls;
            m_[r] = mnew;
            O[0][r] *= alpha; O[1][r] *= alpha; O[2][r] *= alpha; O[3][r] *= alpha;
        }
        __syncthreads();   // P writes -> A-layout reads (conservative ordering)
        // ---- P as A-operand: P[m=l16][kseq = h*32 + quad*8 + j] ----
        bf16x8 pf0 = *(const bf16x8*)(&P_lds[w][l16][quad << 3]);
        bf16x8 pf1 = *(const bf16x8*)(&P_lds[w][l16][32 + (quad << 3)]);
        // ---- O += P V : B-operand = V^T[d = dt*16+l16][kseq] from xT ----
        #pragma unroll
        for (int dt = 0; dt < 4; ++dt) {
            const unsigned short* vr = xb + (((dt << 4) + l16) << 12) + k0 + (quad << 3);
            bf16x8 vf0 = *(const bf16x8*)(vr);
            bf16x8 vf1 = *(const bf16x8*)(vr + 32);
            O[dt] = mfma_bf16(pf0, vf0, O[dt]);
            O[dt] = mfma_bf16(pf1, vf1, O[dt]);
        }
        __syncthreads();
    }
    // ---- epilogue: normalize and store fp32 x_g2 ----
    #pragma unroll
    for (int r = 0; r < 4; ++r) {
        float inv = 1.0f / l_[r];
        int q = qbase + (quad << 2) + r;
        #pragma unroll
        for (int dt = 0; dt < 4; ++dt) {
            xg2[(((size_t)(bt << 12) + q) << 6) + (dt << 4) + l16] = O[dt][r] * inv;
        }
    }
}

// ---------------- Stage C: out = x*W0 + xg2*W1 + bias ----------------------
// Block owns 8 nodes. Thread t: o = t&63, ki subset {t>>6 + 4j}.
__global__ __launch_bounds__(256) void k_out(const float* __restrict__ x,
                                             const float* __restrict__ xg2,
                                             const float* __restrict__ node_emb,
                                             const float* __restrict__ wp,
                                             const float* __restrict__ time_emb,
                                             const float* __restrict__ bias_pool,
                                             float* __restrict__ out) {
    __shared__ float ne_s[8][64];
    __shared__ float xg_s[6][8][128];
    __shared__ float bias_s[6][64];
    __shared__ float red_s[4][64][13];
    const int t  = threadIdx.x;
    const int n0 = blockIdx.x << 3;

    for (int idx = t; idx < 512; idx += 256)
        ne_s[idx >> 6][idx & 63] = node_emb[(n0 << 6) + idx];
    for (int idx = t; idx < 3072; idx += 256) {
        int bt = idx >> 9;
        int g  = (idx >> 6) & 7;
        int i  = idx & 63;
        size_t base = (((size_t)(bt << 12)) + n0 + g) << 6;
        xg_s[bt][g][i]      = x[base + i];
        xg_s[bt][g][64 + i] = xg2[base + i];
    }
    for (int idx = t; idx < 384; idx += 256) {
        int bt = idx >> 6, o = idx & 63;
        float b = 0.f;
        for (int d = 0; d < 64; ++d)
            b += time_emb[(bt << 6) + d] * bias_pool[(d << 6) + o];
        bias_s[bt][o] = b;
    }
    __syncthreads();

    const int o  = t & 63;
    const int q4 = t >> 6;
    float oacc[8][6];
    #pragma unroll
    for (int g = 0; g < 8; ++g)
        #pragma unroll
        for (int bt = 0; bt < 6; ++bt) oacc[g][bt] = 0.f;

    for (int j = 0; j < 32; ++j) {
        int ki = q4 + (j << 2);
        const float* wcol = wp + (ki << 6) + o;
        float acc[8];
        #pragma unroll
        for (int g = 0; g < 8; ++g) acc[g] = 0.f;
        #pragma unroll 16
        for (int d = 0; d < 64; ++d) {
            float wv = wcol[d << 13];   // wp[d][ki*64+o], row stride 8192
            #pragma unroll
            for (int g = 0; g < 8; ++g) acc[g] += ne_s[g][d] * wv;
        }
        #pragma unroll
        for (int g = 0; g < 8; ++g) {
            float a = acc[g];
            #pragma unroll
            for (int bt = 0; bt < 6; ++bt) oacc[g][bt] += xg_s[bt][g][ki] * a;
        }
    }
    // 4 reduction passes, 2 nodes each: sum the 4-way ki split, add bias
    for (int p = 0; p < 4; ++p) {
        __syncthreads();
        #pragma unroll
        for (int gg = 0; gg < 2; ++gg)
            #pragma unroll
            for (int bt = 0; bt < 6; ++bt)
                red_s[q4][o][gg * 6 + bt] = oacc[p * 2 + gg][bt];
        __syncthreads();
        for (int idx = t; idx < 768; idx += 256) {
            int gg  = (idx >= 384) ? 1 : 0;
            int bto = idx - gg * 384;
            int bt = bto >> 6, o2 = bto & 63;
            int s = gg * 6 + bt;
            float v = red_s[0][o2][s] + red_s[1][o2][s] +
                      red_s[2][o2][s] + red_s[3][o2][s] + bias_s[bt][o2];
            out[((((size_t)(bt << 12)) + n0 + (p * 2 + gg)) << 6) + o2] = v;
        }
    }
}

// ---------------------------------------------------------------------------
extern "C" void kernel_launch(void* const* d_in, const int* in_sizes, int n_in,
                              void* d_out, int out_size, void* d_ws, size_t ws_size,
                              hipStream_t stream) {
    const float* x         = (const float*)d_in[0];
    const float* node_emb  = (const float*)d_in[1];
    const float* time_emb  = (const float*)d_in[2];
    const float* wp        = (const float*)d_in[3];
    const float* bias_pool = (const float*)d_in[4];
    const float* gamma     = (const float*)d_in[5];
    const float* beta      = (const float*)d_in[6];
    float* out = (float*)d_out;

    const size_t NE = 6u * 4096u * 64u;              // 1,572,864
    unsigned short* e_bf = (unsigned short*)d_ws;    // bf16 e
    unsigned short* xT   = e_bf + NE;                // bf16 x^T
    float* xg2           = (float*)(xT + NE);        // fp32 x_g2
    // total ws use: 2*2*NE + 4*NE = 12.6 MB

    k_ln<<<6144, 256, 0, stream>>>(node_emb, time_emb, gamma, beta, e_bf);
    k_xt<<<6144, 256, 0, stream>>>(x, xT);
    dim3 ga(64, 6);
    k_attn<<<ga, 256, 0, stream>>>(e_bf, xT, xg2);
    k_out<<<512, 256, 0, stream>>>(x, xg2, node_emb, wp, time_emb, bias_pool, out);
}

// Round 2
// 372.069 us; speedup vs baseline: 2.4088x; 2.4088x over previous
//
#include <hip/hip_runtime.h>

// ---------------------------------------------------------------------------
// DSTGCN fused pipeline, MI355X gfx950.
// Stages: (A) LayerNorm(node_emb + time_emb) -> e (bf16)
//         (X) transpose x -> xT (bf16) for PV B-operand
//         (B) flash attention x_g2 = softmax(e e^T) x   [bf16 MFMA, fp32 acc]
//         (C) hypernet: out = x*W0 + xg2*W1 + bias with W = ne . wp computed
//             on the fly in MFMA C-layout registers (never materialized).
// ---------------------------------------------------------------------------

using bf16x8 = __attribute__((ext_vector_type(8))) __bf16;
using f32x4  = __attribute__((ext_vector_type(4))) float;

__device__ __forceinline__ unsigned short f2bf_bits(float f) {
    unsigned int u = __float_as_uint(f);
    u += 0x7fffu + ((u >> 16) & 1u);          // RNE
    return (unsigned short)(u >> 16);
}

__device__ __forceinline__ f32x4 mfma_bf16(bf16x8 a, bf16x8 b, f32x4 c) {
    return __builtin_amdgcn_mfma_f32_16x16x32_bf16(a, b, c, 0, 0, 0);
}

// ---------------- Stage A: e = LN(node_emb + time_emb), bf16 out -----------
__global__ __launch_bounds__(256) void k_ln(const float* __restrict__ node_emb,
                                            const float* __restrict__ time_emb,
                                            const float* __restrict__ gamma,
                                            const float* __restrict__ beta,
                                            unsigned short* __restrict__ e_bf) {
    int row  = blockIdx.x * 4 + (threadIdx.x >> 6);   // 0..24575 = bt*4096+n
    int lane = threadIdx.x & 63;                      // d index
    int bt = row >> 12, n = row & 4095;
    float v  = node_emb[(n << 6) | lane] + time_emb[(bt << 6) | lane];
    float s = v, s2 = v * v;
    #pragma unroll
    for (int off = 32; off; off >>= 1) {
        s  += __shfl_xor(s,  off);
        s2 += __shfl_xor(s2, off);
    }
    float mu  = s * 0.015625f;
    float var = s2 * 0.015625f - mu * mu;
    float r   = rsqrtf(var + 1e-12f);
    float o   = (v - mu) * r * gamma[lane] + beta[lane];
    e_bf[(row << 6) | lane] = f2bf_bits(o);
}

// ---------------- Stage X: xT[bt][d][n] = bf16(x[bt][n][d]) ----------------
__global__ __launch_bounds__(256) void k_xt(const float* __restrict__ x,
                                            unsigned short* __restrict__ xT) {
    int idx = blockIdx.x * 256 + threadIdx.x;   // over 6*64*4096
    int bt  = idx >> 18;
    int rem = idx & 262143;
    int d   = rem >> 12;
    int n   = rem & 4095;
    xT[idx] = f2bf_bits(x[(((bt << 12) | n) << 6) | d]);
}

// ---------------- Stage B: flash attention (per-wave 16 q rows) ------------
__global__ __launch_bounds__(256) void k_attn(const unsigned short* __restrict__ e_bf,
                                              const unsigned short* __restrict__ xT,
                                              float* __restrict__ xg2) {
    __shared__ __align__(16) unsigned short P_lds[4][16][72];  // per-wave P, padded
    const int bt   = blockIdx.y;
    const int w    = threadIdx.x >> 6;
    const int lane = threadIdx.x & 63;
    const int l16  = lane & 15;
    const int quad = lane >> 4;
    const int qbase = (blockIdx.x << 6) + (w << 4);

    const unsigned short* eb = e_bf + ((size_t)bt << 18);  // bt*4096*64
    const unsigned short* xb = xT   + ((size_t)bt << 18);

    bf16x8 qf0 = *(const bf16x8*)(eb + ((qbase + l16) << 6) + (quad << 3));
    bf16x8 qf1 = *(const bf16x8*)(eb + ((qbase + l16) << 6) + 32 + (quad << 3));

    f32x4 O[4];
    float m_[4], l_[4];
    #pragma unroll
    for (int r = 0; r < 4; ++r) {
        O[r] = f32x4{0.f, 0.f, 0.f, 0.f};
        m_[r] = -1e30f; l_[r] = 0.f;
    }

    for (int kt = 0; kt < 64; ++kt) {
        const int k0 = kt << 6;
        f32x4 S[4];
        #pragma unroll
        for (int ct = 0; ct < 4; ++ct) {
            const unsigned short* kr = eb + ((k0 + (ct << 4) + l16) << 6) + (quad << 3);
            bf16x8 kf0 = *(const bf16x8*)(kr);
            bf16x8 kf1 = *(const bf16x8*)(kr + 32);
            f32x4 acc = f32x4{0.f, 0.f, 0.f, 0.f};
            acc = mfma_bf16(qf0, kf0, acc);
            acc = mfma_bf16(qf1, kf1, acc);
            S[ct] = acc;
        }
        #pragma unroll
        for (int r = 0; r < 4; ++r) {
            float mt = fmaxf(fmaxf(S[0][r], S[1][r]), fmaxf(S[2][r], S[3][r]));
            mt = fmaxf(mt, __shfl_xor(mt, 1));
            mt = fmaxf(mt, __shfl_xor(mt, 2));
            mt = fmaxf(mt, __shfl_xor(mt, 4));
            mt = fmaxf(mt, __shfl_xor(mt, 8));
            float mnew  = fmaxf(m_[r], mt);
            float alpha = __expf(m_[r] - mnew);
            float ls = 0.f;
            #pragma unroll
            for (int ct = 0; ct < 4; ++ct) {
                float p = __expf(S[ct][r] - mnew);
                ls += p;
                P_lds[w][(quad << 2) + r][(ct << 4) + l16] = f2bf_bits(p);
            }
            ls += __shfl_xor(ls, 1);
            ls += __shfl_xor(ls, 2);
            ls += __shfl_xor(ls, 4);
            ls += __shfl_xor(ls, 8);
            l_[r] = l_[r] * alpha + ls;
            m_[r] = mnew;
            O[0][r] *= alpha; O[1][r] *= alpha; O[2][r] *= alpha; O[3][r] *= alpha;
        }
        __syncthreads();
        bf16x8 pf0 = *(const bf16x8*)(&P_lds[w][l16][quad << 3]);
        bf16x8 pf1 = *(const bf16x8*)(&P_lds[w][l16][32 + (quad << 3)]);
        #pragma unroll
        for (int dt = 0; dt < 4; ++dt) {
            const unsigned short* vr = xb + (((dt << 4) + l16) << 12) + k0 + (quad << 3);
            bf16x8 vf0 = *(const bf16x8*)(vr);
            bf16x8 vf1 = *(const bf16x8*)(vr + 32);
            O[dt] = mfma_bf16(pf0, vf0, O[dt]);
            O[dt] = mfma_bf16(pf1, vf1, O[dt]);
        }
        __syncthreads();
    }
    #pragma unroll
    for (int r = 0; r < 4; ++r) {
        float inv = 1.0f / l_[r];
        int q = qbase + (quad << 2) + r;
        #pragma unroll
        for (int dt = 0; dt < 4; ++dt) {
            xg2[(((size_t)(bt << 12) + q) << 6) + (dt << 4) + l16] = O[dt][r] * inv;
        }
    }
}

// ---------------- Pre-pass: ne_bf[n][d] = bf16(node_emb) -------------------
__global__ __launch_bounds__(256) void k_ne(const float* __restrict__ node_emb,
                                            unsigned short* __restrict__ ne_bf) {
    int idx = blockIdx.x * 256 + threadIdx.x;   // 262144
    ne_bf[idx] = f2bf_bits(node_emb[idx]);
}

// ---------------- Pre-pass: wpT[ki][o][d] = bf16(wp[d][ki][o]) -------------
__global__ __launch_bounds__(256) void k_wpT(const float* __restrict__ wp,
                                             unsigned short* __restrict__ wpT) {
    __shared__ float tile[64][65];
    const int ki = blockIdx.x;            // 0..127
    const int t  = threadIdx.x;
    #pragma unroll
    for (int it = 0; it < 16; ++it) {
        int d = (it << 2) + (t >> 6);
        int o = t & 63;
        tile[d][o] = wp[(d << 13) + (ki << 6) + o];
    }
    __syncthreads();
    #pragma unroll
    for (int j = 0; j < 16; ++j) {
        int idx = (j << 8) + t;           // 0..4095
        int o = idx >> 6, d = idx & 63;
        wpT[((ki << 6) + o << 6) + d] = f2bf_bits(tile[d][o]);
    }
}

// ---------------- Pre-pass: bias[bt][o] = time_emb[bt].bias_pool[:,o] ------
__global__ __launch_bounds__(384) void k_bias(const float* __restrict__ time_emb,
                                              const float* __restrict__ bias_pool,
                                              float* __restrict__ bias_ws) {
    int t = threadIdx.x;          // 0..383
    int bt = t >> 6, o = t & 63;
    float b = 0.f;
    for (int d = 0; d < 64; ++d)
        b += time_emb[(bt << 6) + d] * bias_pool[(d << 6) + o];
    bias_ws[t] = b;
}

// ---------------- Stage C: fused hypernetwork contraction ------------------
// Block: 256 thr = 4 waves; owns 16 nodes x one o-half (32 o). Wave w handles
// ki quarter [w*32, w*32+32). W subtile = mfma(ne_tile, wpT cols) in C-layout
// regs, consumed immediately: oac[oc][r][bt] += W[n][ki][o] * xg[bt][n][ki].
// Cross-kq reduction + bias in LDS epilogue.
__global__ __launch_bounds__(256, 2) void k_hyper(const float* __restrict__ x,
                                                  const float* __restrict__ xg2,
                                                  const unsigned short* __restrict__ ne_bf,
                                                  const unsigned short* __restrict__ wpT,
                                                  const float* __restrict__ bias_ws,
                                                  float* __restrict__ out) {
    __shared__ float smem[13056];          // 52.2 KB: xg (4x3104) then red (4x3264)
    const int t    = threadIdx.x;
    const int w    = t >> 6;
    const int lane = t & 63;
    const int l16  = lane & 15;
    const int quad = lane >> 4;
    const int n0   = (blockIdx.x >> 1) << 4;
    const int oh   = blockIdx.x & 1;       // o-half

    // ---- stage this wave's xg slice: xg_s[kk][nl*6+bt], row stride 97 ----
    float* xg_s = smem + w * 3104;
    const float* src = (w < 2) ? x : xg2;
    const int i0 = (w & 1) << 5;
    for (int it = 0; it < 48; ++it) {
        int j  = (it << 6) + lane;         // 0..3071
        int kk = j & 31;
        int btnl = j >> 5;                 // 0..95
        int bt = btnl % 6;
        int nl = btnl / 6;
        xg_s[kk * 97 + btnl] =
            src[(((size_t)(bt << 12) + n0 + nl) << 6) + i0 + kk];
    }
    __syncthreads();

    // ---- resident A fragments: 16 nodes ----
    const unsigned short* nb = ne_bf + ((n0 + l16) << 6) + (quad << 3);
    bf16x8 a0 = *(const bf16x8*)(nb);
    bf16x8 a1 = *(const bf16x8*)(nb + 32);

    float oac[2][4][6];
    #pragma unroll
    for (int oc = 0; oc < 2; ++oc)
        #pragma unroll
        for (int r = 0; r < 4; ++r)
            #pragma unroll
            for (int bt = 0; bt < 6; ++bt) oac[oc][r][bt] = 0.f;

    const int ki_base = w << 5;
    #pragma unroll 2
    for (int kk = 0; kk < 32; ++kk) {
        const int ki = ki_base + kk;
        float g[4][6];
        #pragma unroll
        for (int r = 0; r < 4; ++r) {
            const float* gp = xg_s + kk * 97 + ((quad << 2) + r) * 6;
            #pragma unroll
            for (int bt = 0; bt < 6; ++bt) g[r][bt] = gp[bt];
        }
        #pragma unroll
        for (int oc = 0; oc < 2; ++oc) {
            const unsigned short* bp =
                wpT + (((ki << 6) + ((oh * 2 + oc) << 4) + l16) << 6) + (quad << 3);
            bf16x8 b0 = *(const bf16x8*)(bp);
            bf16x8 b1 = *(const bf16x8*)(bp + 32);
            f32x4 wf = mfma_bf16(a0, b0, f32x4{0.f, 0.f, 0.f, 0.f});
            wf = mfma_bf16(a1, b1, wf);
            #pragma unroll
            for (int r = 0; r < 4; ++r)
                #pragma unroll
                for (int bt = 0; bt < 6; ++bt)
                    oac[oc][r][bt] += wf[r] * g[r][bt];
        }
    }

    // ---- epilogue: red[kq][nl][bt][34], reduce over kq, add bias, store ----
    __syncthreads();                        // xg_s dead; smem becomes red
    #pragma unroll
    for (int oc = 0; oc < 2; ++oc)
        #pragma unroll
        for (int r = 0; r < 4; ++r)
            #pragma unroll
            for (int bt = 0; bt < 6; ++bt)
                smem[w * 3264 + ((quad << 2) + r) * 204 + bt * 34 + (oc << 4) + l16]
                    = oac[oc][r][bt];
    __syncthreads();
    #pragma unroll
    for (int rr = 0; rr < 4; ++rr) {
        int nl = (w << 2) + rr;
        #pragma unroll
        for (int bp2 = 0; bp2 < 3; ++bp2) {
            int bt = bp2 * 2 + (lane >> 5);
            int ol = lane & 31;
            int o  = (oh << 5) + ol;
            int a  = nl * 204 + bt * 34 + ol;
            float v = smem[a] + smem[a + 3264] + smem[a + 6528] + smem[a + 9792]
                    + bias_ws[(bt << 6) + o];
            out[(((size_t)(bt << 12) + n0 + nl) << 6) + o] = v;
        }
    }
}

// ---------------------------------------------------------------------------
extern "C" void kernel_launch(void* const* d_in, const int* in_sizes, int n_in,
                              void* d_out, int out_size, void* d_ws, size_t ws_size,
                              hipStream_t stream) {
    const float* x         = (const float*)d_in[0];
    const float* node_emb  = (const float*)d_in[1];
    const float* time_emb  = (const float*)d_in[2];
    const float* wp        = (const float*)d_in[3];
    const float* bias_pool = (const float*)d_in[4];
    const float* gamma     = (const float*)d_in[5];
    const float* beta      = (const float*)d_in[6];
    float* out = (float*)d_out;

    const size_t NE = 6u * 4096u * 64u;              // 1,572,864
    char* wsb = (char*)d_ws;
    unsigned short* e_bf  = (unsigned short*)(wsb);                  // 3 MB
    unsigned short* xT    = (unsigned short*)(wsb + 3145728);        // 3 MB
    float*          xg2   = (float*)         (wsb + 6291456);        // 6.3 MB
    unsigned short* wpT   = (unsigned short*)(wsb + 12582912);       // 1 MB
    unsigned short* ne_bf = (unsigned short*)(wsb + 13631488);       // 0.5 MB
    float*          biasw = (float*)         (wsb + 14155776);       // 1.5 KB
    (void)NE;

    k_ln  <<<6144, 256, 0, stream>>>(node_emb, time_emb, gamma, beta, e_bf);
    k_xt  <<<6144, 256, 0, stream>>>(x, xT);
    k_ne  <<<1024, 256, 0, stream>>>(node_emb, ne_bf);
    k_wpT <<<128,  256, 0, stream>>>(wp, wpT);
    k_bias<<<1,    384, 0, stream>>>(time_emb, bias_pool, biasw);
    dim3 ga(64, 6);
    k_attn<<<ga, 256, 0, stream>>>(e_bf, xT, xg2);
    k_hyper<<<512, 256, 0, stream>>>(x, xg2, ne_bf, wpT, biasw, out);
}

// Round 3
// 215.654 us; speedup vs baseline: 4.1559x; 1.7253x over previous
//
#include <hip/hip_runtime.h>

// ---------------------------------------------------------------------------
// DSTGCN fused pipeline, MI355X gfx950.
// (A) LayerNorm(node_emb + time_emb) -> e (bf16) + eq (bf16, pre-scaled log2e)
// (X) transpose x -> xT (bf16)
// (B) flash attention, no-max softmax (logits bounded by LN: |S|<=64),
//     32x32x16 bf16 MFMA, in-block 4-way key split, zero barriers in K-loop.
// (C) hypernet: out = x*W0 + xg2*W1 + bias, W on the fly in MFMA regs.
// ---------------------------------------------------------------------------

using bf16x8 = __attribute__((ext_vector_type(8))) __bf16;
using f32x4  = __attribute__((ext_vector_type(4))) float;
using f32x16 = __attribute__((ext_vector_type(16))) float;

__device__ __forceinline__ unsigned short f2bf_bits(float f) {
    unsigned int u = __float_as_uint(f);
    u += 0x7fffu + ((u >> 16) & 1u);          // RNE
    return (unsigned short)(u >> 16);
}

__device__ __forceinline__ f32x4 mfma16(bf16x8 a, bf16x8 b, f32x4 c) {
    return __builtin_amdgcn_mfma_f32_16x16x32_bf16(a, b, c, 0, 0, 0);
}
__device__ __forceinline__ f32x16 mfma32(bf16x8 a, bf16x8 b, f32x16 c) {
    return __builtin_amdgcn_mfma_f32_32x32x16_bf16(a, b, c, 0, 0, 0);
}
__device__ __forceinline__ f32x16 zero16() {
    f32x16 z;
    #pragma unroll
    for (int i = 0; i < 16; ++i) z[i] = 0.f;
    return z;
}

// ---------------- Stage A: e = LN(node_emb + time_emb) ---------------------
__global__ __launch_bounds__(256) void k_ln(const float* __restrict__ node_emb,
                                            const float* __restrict__ time_emb,
                                            const float* __restrict__ gamma,
                                            const float* __restrict__ beta,
                                            unsigned short* __restrict__ e_bf,
                                            unsigned short* __restrict__ eq_bf) {
    int row  = blockIdx.x * 4 + (threadIdx.x >> 6);   // bt*4096+n
    int lane = threadIdx.x & 63;                      // d index
    int bt = row >> 12, n = row & 4095;
    float v  = node_emb[(n << 6) | lane] + time_emb[(bt << 6) | lane];
    float s = v, s2 = v * v;
    #pragma unroll
    for (int off = 32; off; off >>= 1) {
        s  += __shfl_xor(s,  off);
        s2 += __shfl_xor(s2, off);
    }
    float mu  = s * 0.015625f;
    float var = s2 * 0.015625f - mu * mu;
    float r   = rsqrtf(var + 1e-12f);
    float o   = (v - mu) * r * gamma[lane] + beta[lane];
    e_bf [(row << 6) | lane] = f2bf_bits(o);
    eq_bf[(row << 6) | lane] = f2bf_bits(o * 1.44269504f);   // log2(e)
}

// ---------------- Stage X: xT[bt][d][n] = bf16(x[bt][n][d]) ----------------
__global__ __launch_bounds__(256) void k_xt(const float* __restrict__ x,
                                            unsigned short* __restrict__ xT) {
    int idx = blockIdx.x * 256 + threadIdx.x;   // over 6*64*4096
    int bt  = idx >> 18;
    int rem = idx & 262143;
    int d   = rem >> 12;
    int n   = rem & 4095;
    xT[idx] = f2bf_bits(x[(((bt << 12) | n) << 6) | d]);
}

// ---------------- Stage B: flash attention -------------------------------
// Block = 4 waves, 32 q rows. Wave w handles keys [w*1024, w*1024+1024).
// No-max softmax: P = exp(S) directly (|S| <= 64, safe in fp32/bf16).
// P round-trip per-wave in LDS (in-order DS + lgkmcnt fence, no barriers).
// Single __syncthreads to merge 4 partial (O,l) via reused P region.
__global__ __launch_bounds__(256, 3) void k_attn(const unsigned short* __restrict__ e_bf,
                                                 const unsigned short* __restrict__ eq_bf,
                                                 const unsigned short* __restrict__ xT,
                                                 float* __restrict__ xg2) {
    __shared__ __align__(16) unsigned short P_all[4 * 32 * 136];  // 34.8 KB
    __shared__ float l_s[4][32];
    const int tid  = threadIdx.x;
    const int w    = tid >> 6;
    const int lane = tid & 63;
    const int l32  = lane & 31;
    const int h    = lane >> 5;

    // XCD-aware swizzle: blocks with same (bt, q-quarter) land on one XCD.
    const int bid   = blockIdx.x;          // 0..767
    const int x8    = bid & 7;
    const int g     = (bid >> 3) & 31;
    const int r3    = bid >> 8;            // 0..2
    const int combo = x8 * 3 + r3;         // 0..23
    const int bt    = combo >> 2;
    const int qb    = ((combo & 3) << 5) + g;   // 0..127
    const int qbase = qb << 5;                  // 32 q rows

    const unsigned short* eb  = e_bf  + ((size_t)bt << 18);
    const unsigned short* eqb = eq_bf + ((size_t)bt << 18);
    const unsigned short* xb  = xT    + ((size_t)bt << 18);
    unsigned short* P_w = P_all + w * 4352;     // 32 rows x 136 shorts

    // Q A-frags (pre-scaled), 4 K=16 chunks: A[m=l32][k=h*8+j] at d=c*16
    bf16x8 qf[4];
    #pragma unroll
    for (int c = 0; c < 4; ++c)
        qf[c] = *(const bf16x8*)(eqb + ((qbase + l32) << 6) + (c << 4) + (h << 3));

    f32x16 O0 = zero16(), O1 = zero16();
    float ls[16];
    #pragma unroll
    for (int i = 0; i < 16; ++i) ls[i] = 0.f;

    const int kstart = w << 10;
    for (int t = 0; t < 8; ++t) {
        const int k0 = kstart + (t << 7);          // 128-key tile
        // ---- S phase: 4 key-groups of 32 ----
        #pragma unroll
        for (int kg = 0; kg < 4; ++kg) {
            const unsigned short* kr =
                eb + ((size_t)(k0 + (kg << 5) + l32) << 6) + (h << 3);
            f32x16 S = zero16();
            #pragma unroll
            for (int c = 0; c < 4; ++c) {
                bf16x8 kf = *(const bf16x8*)(kr + (c << 4));
                S = mfma32(qf[c], kf, S);
            }
            // C-layout: col(key)=l32, row(q)=(rg&3)+8*(rg>>2)+4*h
            #pragma unroll
            for (int rg = 0; rg < 16; ++rg) {
                float p = exp2f(S[rg]);
                ls[rg] += p;
                int qrow = (rg & 3) + ((rg >> 2) << 3) + (h << 2);
                P_w[qrow * 136 + (kg << 5) + l32] = f2bf_bits(p);
            }
        }
        asm volatile("s_waitcnt lgkmcnt(0)" ::: "memory");  // P visible to own wave
        // ---- PV phase: O += P V, 8 K=16 chunks x 2 d-halves ----
        #pragma unroll
        for (int kc = 0; kc < 8; ++kc) {
            bf16x8 pf = *(const bf16x8*)(P_w + l32 * 136 + (kc << 4) + (h << 3));
            const unsigned short* vr =
                xb + ((size_t)l32 << 12) + k0 + (kc << 4) + (h << 3);
            bf16x8 v0 = *(const bf16x8*)(vr);
            bf16x8 v1 = *(const bf16x8*)(vr + (32 << 12));
            O0 = mfma32(pf, v0, O0);
            O1 = mfma32(pf, v1, O1);
        }
    }

    // ---- per-wave l reduction across the 32 key-lanes ----
    #pragma unroll
    for (int rg = 0; rg < 16; ++rg) {
        float v = ls[rg];
        v += __shfl_xor(v, 1);  v += __shfl_xor(v, 2);
        v += __shfl_xor(v, 4);  v += __shfl_xor(v, 8);
        v += __shfl_xor(v, 16);
        ls[rg] = v;
    }
    if (l32 == 0) {
        #pragma unroll
        for (int rg = 0; rg < 16; ++rg) {
            int qrow = (rg & 3) + ((rg >> 2) << 3) + (h << 2);
            l_s[w][qrow] = ls[rg];
        }
    }
    // ---- dump partial O into own P region (as float [32][68]) ----
    asm volatile("s_waitcnt lgkmcnt(0)" ::: "memory");
    float* O_s = (float*)P_w;
    #pragma unroll
    for (int rg = 0; rg < 16; ++rg) {
        int qrow = (rg & 3) + ((rg >> 2) << 3) + (h << 2);
        O_s[qrow * 68 + l32]      = O0[rg];
        O_s[qrow * 68 + 32 + l32] = O1[rg];
    }
    __syncthreads();
    // ---- merge 4 waves, normalize, store ----
    {
        int q  = tid >> 3;
        int d0 = (tid & 7) << 3;
        float lsum = l_s[0][q] + l_s[1][q] + l_s[2][q] + l_s[3][q];
        float acc[8];
        #pragma unroll
        for (int i = 0; i < 8; ++i) acc[i] = 0.f;
        #pragma unroll
        for (int ww = 0; ww < 4; ++ww) {
            const float* Ow = (const float*)(P_all + ww * 4352) + q * 68 + d0;
            #pragma unroll
            for (int i = 0; i < 8; ++i) acc[i] += Ow[i];
        }
        float inv = 1.f / lsum;
        float* dst = xg2 + (((size_t)(bt << 12) + qbase + q) << 6) + d0;
        #pragma unroll
        for (int i = 0; i < 8; ++i) dst[i] = acc[i] * inv;
    }
}

// ---------------- Pre-pass: ne_bf[n][d] = bf16(node_emb) -------------------
__global__ __launch_bounds__(256) void k_ne(const float* __restrict__ node_emb,
                                            unsigned short* __restrict__ ne_bf) {
    int idx = blockIdx.x * 256 + threadIdx.x;   // 262144
    ne_bf[idx] = f2bf_bits(node_emb[idx]);
}

// ---------------- Pre-pass: wpT[ki][o][d] = bf16(wp[d][ki][o]) -------------
__global__ __launch_bounds__(256) void k_wpT(const float* __restrict__ wp,
                                             unsigned short* __restrict__ wpT) {
    __shared__ float tile[64][65];
    const int ki = blockIdx.x;            // 0..127
    const int t  = threadIdx.x;
    #pragma unroll
    for (int it = 0; it < 16; ++it) {
        int d = (it << 2) + (t >> 6);
        int o = t & 63;
        tile[d][o] = wp[(d << 13) + (ki << 6) + o];
    }
    __syncthreads();
    #pragma unroll
    for (int j = 0; j < 16; ++j) {
        int idx = (j << 8) + t;           // 0..4095
        int o = idx >> 6, d = idx & 63;
        wpT[((ki << 6) + o << 6) + d] = f2bf_bits(tile[d][o]);
    }
}

// ---------------- Pre-pass: bias[bt][o] = time_emb[bt].bias_pool[:,o] ------
__global__ __launch_bounds__(384) void k_bias(const float* __restrict__ time_emb,
                                              const float* __restrict__ bias_pool,
                                              float* __restrict__ bias_ws) {
    int t = threadIdx.x;          // 0..383
    int bt = t >> 6, o = t & 63;
    float b = 0.f;
    for (int d = 0; d < 64; ++d)
        b += time_emb[(bt << 6) + d] * bias_pool[(d << 6) + o];
    bias_ws[t] = b;
}

// ---------------- Stage C: fused hypernetwork contraction ------------------
__global__ __launch_bounds__(256, 2) void k_hyper(const float* __restrict__ x,
                                                  const float* __restrict__ xg2,
                                                  const unsigned short* __restrict__ ne_bf,
                                                  const unsigned short* __restrict__ wpT,
                                                  const float* __restrict__ bias_ws,
                                                  float* __restrict__ out) {
    __shared__ float smem[13056];          // 52.2 KB: xg (4x3104) then red (4x3264)
    const int t    = threadIdx.x;
    const int w    = t >> 6;
    const int lane = t & 63;
    const int l16  = lane & 15;
    const int quad = lane >> 4;
    const int n0   = (blockIdx.x >> 1) << 4;
    const int oh   = blockIdx.x & 1;       // o-half

    float* xg_s = smem + w * 3104;
    const float* src = (w < 2) ? x : xg2;
    const int i0 = (w & 1) << 5;
    for (int it = 0; it < 48; ++it) {
        int j  = (it << 6) + lane;         // 0..3071
        int kk = j & 31;
        int btnl = j >> 5;                 // 0..95
        int bt = btnl % 6;
        int nl = btnl / 6;
        xg_s[kk * 97 + btnl] =
            src[(((size_t)(bt << 12) + n0 + nl) << 6) + i0 + kk];
    }
    __syncthreads();

    const unsigned short* nb = ne_bf + ((n0 + l16) << 6) + (quad << 3);
    bf16x8 a0 = *(const bf16x8*)(nb);
    bf16x8 a1 = *(const bf16x8*)(nb + 32);

    float oac[2][4][6];
    #pragma unroll
    for (int oc = 0; oc < 2; ++oc)
        #pragma unroll
        for (int r = 0; r < 4; ++r)
            #pragma unroll
            for (int bt = 0; bt < 6; ++bt) oac[oc][r][bt] = 0.f;

    const int ki_base = w << 5;
    #pragma unroll 2
    for (int kk = 0; kk < 32; ++kk) {
        const int ki = ki_base + kk;
        float g[4][6];
        #pragma unroll
        for (int r = 0; r < 4; ++r) {
            const float* gp = xg_s + kk * 97 + ((quad << 2) + r) * 6;
            #pragma unroll
            for (int bt = 0; bt < 6; ++bt) g[r][bt] = gp[bt];
        }
        #pragma unroll
        for (int oc = 0; oc < 2; ++oc) {
            const unsigned short* bp =
                wpT + (((ki << 6) + ((oh * 2 + oc) << 4) + l16) << 6) + (quad << 3);
            bf16x8 b0 = *(const bf16x8*)(bp);
            bf16x8 b1 = *(const bf16x8*)(bp + 32);
            f32x4 wf = mfma16(a0, b0, f32x4{0.f, 0.f, 0.f, 0.f});
            wf = mfma16(a1, b1, wf);
            #pragma unroll
            for (int r = 0; r < 4; ++r)
                #pragma unroll
                for (int bt = 0; bt < 6; ++bt)
                    oac[oc][r][bt] += wf[r] * g[r][bt];
        }
    }

    __syncthreads();                        // xg_s dead; smem becomes red
    #pragma unroll
    for (int oc = 0; oc < 2; ++oc)
        #pragma unroll
        for (int r = 0; r < 4; ++r)
            #pragma unroll
            for (int bt = 0; bt < 6; ++bt)
                smem[w * 3264 + ((quad << 2) + r) * 204 + bt * 34 + (oc << 4) + l16]
                    = oac[oc][r][bt];
    __syncthreads();
    #pragma unroll
    for (int rr = 0; rr < 4; ++rr) {
        int nl = (w << 2) + rr;
        #pragma unroll
        for (int bp2 = 0; bp2 < 3; ++bp2) {
            int bt = bp2 * 2 + (lane >> 5);
            int ol = lane & 31;
            int o  = (oh << 5) + ol;
            int a  = nl * 204 + bt * 34 + ol;
            float v = smem[a] + smem[a + 3264] + smem[a + 6528] + smem[a + 9792]
                    + bias_ws[(bt << 6) + o];
            out[(((size_t)(bt << 12) + n0 + nl) << 6) + o] = v;
        }
    }
}

// ---------------------------------------------------------------------------
extern "C" void kernel_launch(void* const* d_in, const int* in_sizes, int n_in,
                              void* d_out, int out_size, void* d_ws, size_t ws_size,
                              hipStream_t stream) {
    const float* x         = (const float*)d_in[0];
    const float* node_emb  = (const float*)d_in[1];
    const float* time_emb  = (const float*)d_in[2];
    const float* wp        = (const float*)d_in[3];
    const float* bias_pool = (const float*)d_in[4];
    const float* gamma     = (const float*)d_in[5];
    const float* beta      = (const float*)d_in[6];
    float* out = (float*)d_out;

    char* wsb = (char*)d_ws;
    unsigned short* e_bf  = (unsigned short*)(wsb);                  // 3 MB
    unsigned short* eq_bf = (unsigned short*)(wsb + 3145728);        // 3 MB
    unsigned short* xT    = (unsigned short*)(wsb + 6291456);        // 3 MB
    float*          xg2   = (float*)         (wsb + 9437184);        // 6.3 MB
    unsigned short* wpT   = (unsigned short*)(wsb + 15728640);       // 1 MB
    unsigned short* ne_bf = (unsigned short*)(wsb + 16777216);       // 0.5 MB
    float*          biasw = (float*)         (wsb + 17301504);       // 1.5 KB

    k_ln  <<<6144, 256, 0, stream>>>(node_emb, time_emb, gamma, beta, e_bf, eq_bf);
    k_xt  <<<6144, 256, 0, stream>>>(x, xT);
    k_ne  <<<1024, 256, 0, stream>>>(node_emb, ne_bf);
    k_wpT <<<128,  256, 0, stream>>>(wp, wpT);
    k_bias<<<1,    384, 0, stream>>>(time_emb, bias_pool, biasw);
    k_attn<<<768, 256, 0, stream>>>(e_bf, eq_bf, xT, xg2);
    k_hyper<<<512, 256, 0, stream>>>(x, xg2, ne_bf, wpT, biasw, out);
}

// Round 4
// 203.461 us; speedup vs baseline: 4.4049x; 1.0599x over previous
//
#include <hip/hip_runtime.h>

// ---------------------------------------------------------------------------
// DSTGCN fused pipeline, MI355X gfx950.
// k_prep : LN(node+time)->e,eq | x->xT (LDS-tiled) | ne_bf | wpT | bias
// k_attn : flash attention, no-max softmax (LN bounds |logit|<=64),
//          S^T = K.Q^T so P exits MFMA with lane=q: PV A-frags built
//          in-register (2 shfl_xor(32) per 32-key group). Zero LDS / zero
//          barriers in the K-loop; single end-merge of 4 key-split waves.
// k_hyper: out = x*W0 + xg2*W1 + bias, W = ne.wp on the fly in MFMA regs.
// ---------------------------------------------------------------------------

using bf16x8 = __attribute__((ext_vector_type(8))) __bf16;
using f32x4  = __attribute__((ext_vector_type(4))) float;
using f32x16 = __attribute__((ext_vector_type(16))) float;

__device__ __forceinline__ unsigned short f2bf_bits(float f) {
    unsigned int u = __float_as_uint(f);
    u += 0x7fffu + ((u >> 16) & 1u);          // RNE
    return (unsigned short)(u >> 16);
}

__device__ __forceinline__ f32x4 mfma16(bf16x8 a, bf16x8 b, f32x4 c) {
    return __builtin_amdgcn_mfma_f32_16x16x32_bf16(a, b, c, 0, 0, 0);
}
__device__ __forceinline__ f32x16 mfma32(bf16x8 a, bf16x8 b, f32x16 c) {
    return __builtin_amdgcn_mfma_f32_32x32x16_bf16(a, b, c, 0, 0, 0);
}
__device__ __forceinline__ f32x16 zero16() {
    f32x16 z;
    #pragma unroll
    for (int i = 0; i < 16; ++i) z[i] = 0.f;
    return z;
}

// ---------------- k_prep: all preprocessing in one launch ------------------
// blocks [0,6144)   : LN -> e_bf, eq_bf          (4 rows/block)
// blocks [6144,6528): x -> xT bf16 transpose      (64n x 64d tile)
// blocks [6528,7552): ne_bf = bf16(node_emb)
// blocks [7552,7680): wpT[ki][o][d] = bf16(wp[d][ki][o])
// block  7680       : bias[bt][o]
__global__ __launch_bounds__(256) void k_prep(const float* __restrict__ x,
                                              const float* __restrict__ node_emb,
                                              const float* __restrict__ time_emb,
                                              const float* __restrict__ wp,
                                              const float* __restrict__ bias_pool,
                                              const float* __restrict__ gamma,
                                              const float* __restrict__ beta,
                                              unsigned short* __restrict__ e_bf,
                                              unsigned short* __restrict__ eq_bf,
                                              unsigned short* __restrict__ xT,
                                              unsigned short* __restrict__ ne_bf,
                                              unsigned short* __restrict__ wpT,
                                              float* __restrict__ biasw) {
    __shared__ float tile[64 * 65];
    const int b = blockIdx.x;
    const int t = threadIdx.x;
    if (b < 6144) {                               // ---- LayerNorm ----
        int row  = b * 4 + (t >> 6);              // bt*4096+n
        int lane = t & 63;
        int bt = row >> 12, n = row & 4095;
        float v = node_emb[(n << 6) | lane] + time_emb[(bt << 6) | lane];
        float s = v, s2 = v * v;
        #pragma unroll
        for (int off = 32; off; off >>= 1) {
            s  += __shfl_xor(s,  off);
            s2 += __shfl_xor(s2, off);
        }
        float mu  = s * 0.015625f;
        float var = s2 * 0.015625f - mu * mu;
        float r   = rsqrtf(var + 1e-12f);
        float o   = (v - mu) * r * gamma[lane] + beta[lane];
        e_bf [(row << 6) | lane] = f2bf_bits(o);
        eq_bf[(row << 6) | lane] = f2bf_bits(o * 1.44269504f);
    } else if (b < 6528) {                        // ---- x transpose ----
        int bb = b - 6144;
        int bt = bb >> 6, n0 = (bb & 63) << 6;
        const float* xr = x + ((size_t)((bt << 12) | n0) << 6);
        #pragma unroll
        for (int it = 0; it < 16; ++it) {
            int i = (it << 2) + (t >> 6);
            int d = t & 63;
            tile[i * 65 + d] = xr[(i << 6) + d];  // coalesced 256B rows
        }
        __syncthreads();
        unsigned short* dst = xT + ((size_t)bt << 18) + n0;
        #pragma unroll
        for (int it = 0; it < 16; ++it) {
            int d = (it << 2) + (t >> 6);
            int n = t & 63;
            dst[((size_t)d << 12) + n] = f2bf_bits(tile[n * 65 + d]);
        }
    } else if (b < 7552) {                        // ---- ne_bf ----
        int idx = (b - 6528) * 256 + t;
        ne_bf[idx] = f2bf_bits(node_emb[idx]);
    } else if (b < 7680) {                        // ---- wpT ----
        int ki = b - 7552;
        #pragma unroll
        for (int it = 0; it < 16; ++it) {
            int d = (it << 2) + (t >> 6);
            int o = t & 63;
            tile[d * 65 + o] = wp[(d << 13) + (ki << 6) + o];
        }
        __syncthreads();
        #pragma unroll
        for (int j = 0; j < 16; ++j) {
            int idx = (j << 8) + t;
            int o = idx >> 6, d = idx & 63;
            wpT[(((ki << 6) + o) << 6) + d] = f2bf_bits(tile[d * 65 + o]);
        }
    } else {                                      // ---- bias ----
        for (int idx = t; idx < 384; idx += 256) {
            int bt = idx >> 6, o = idx & 63;
            float bsum = 0.f;
            for (int d = 0; d < 64; ++d)
                bsum += time_emb[(bt << 6) + d] * bias_pool[(d << 6) + o];
            biasw[idx] = bsum;
        }
    }
}

// ---------------- k_attn: barrier-free flash attention ---------------------
// Block = 4 waves, 32 q rows; wave w owns keys [w*1024, w*1024+1024).
// S^T C-layout: col(lane&31)=q, row=(reg&3)+8*(reg>>2)+4*(lane>>5)=key.
// PV A-frag P[q=lane&31][key=h*8+j] built via half-exchange shfl_xor(32).
__global__ __launch_bounds__(256, 3) void k_attn(const unsigned short* __restrict__ e_bf,
                                                 const unsigned short* __restrict__ eq_bf,
                                                 const unsigned short* __restrict__ xT,
                                                 float* __restrict__ xg2) {
    __shared__ __align__(16) float Obuf[2][32 * 68];   // 17.4 KB merge buffers
    __shared__ float l_s[4][32];
    const int tid  = threadIdx.x;
    const int w    = tid >> 6;
    const int lane = tid & 63;
    const int l32  = lane & 31;
    const int h    = lane >> 5;

    // XCD-aware swizzle (bijective over 768)
    const int bid   = blockIdx.x;
    const int x8    = bid & 7;
    const int g     = (bid >> 3) & 31;
    const int r3    = bid >> 8;
    const int combo = x8 * 3 + r3;               // 0..23
    const int bt    = combo >> 2;
    const int qbase = ((((combo & 3) << 5) + g) << 5);

    const unsigned short* eb  = e_bf  + ((size_t)bt << 18);
    const unsigned short* eqb = eq_bf + ((size_t)bt << 18);
    const unsigned short* xb  = xT    + ((size_t)bt << 18);

    // Q as B-operand (pre-scaled by log2e): lane n=l32=q, k=h*8+j, d=c*16+k
    bf16x8 qf[4];
    #pragma unroll
    for (int c = 0; c < 4; ++c)
        qf[c] = *(const bf16x8*)(eqb + ((qbase + l32) << 6) + (c << 4) + (h << 3));

    f32x16 O0 = zero16(), O1 = zero16();
    float ls = 0.f;

    const int kstart = w << 10;
    for (int gi = 0; gi < 32; ++gi) {
        const int k0 = kstart + (gi << 5);
        // ---- S^T = K . Q^T over 32 keys ----
        const unsigned short* kr = eb + ((size_t)(k0 + l32) << 6) + (h << 3);
        f32x16 S = zero16();
        #pragma unroll
        for (int c = 0; c < 4; ++c) {
            bf16x8 kf = *(const bf16x8*)(kr + (c << 4));
            S = mfma32(kf, qf[c], S);
        }
        // ---- softmax numerator (no max needed: |S| <= 64*log2e) ----
        float p[16];
        #pragma unroll
        for (int r = 0; r < 16; ++r) { p[r] = exp2f(S[r]); ls += p[r]; }
        // ---- half-exchange: build A-frags P[q=l32][key] for 2 K=16 chunks --
        float r0[4], r1[4];
        #pragma unroll
        for (int j = 0; j < 4; ++j) {
            r0[j] = __shfl_xor(h ? p[j]      : p[4 + j],  32);
            r1[j] = __shfl_xor(h ? p[8 + j]  : p[12 + j], 32);
        }
        bf16x8 pf0, pf1;
        #pragma unroll
        for (int j = 0; j < 4; ++j) {
            pf0[j]     = (__bf16)(h ? r0[j]      : p[j]);
            pf0[4 + j] = (__bf16)(h ? p[4 + j]   : r0[j]);
            pf1[j]     = (__bf16)(h ? r1[j]      : p[8 + j]);
            pf1[4 + j] = (__bf16)(h ? p[12 + j]  : r1[j]);
        }
        // ---- PV: B-operand V[key][d=n] from xT rows ----
        const unsigned short* vr = xb + ((size_t)l32 << 12) + k0 + (h << 3);
        bf16x8 va0 = *(const bf16x8*)(vr);
        bf16x8 va1 = *(const bf16x8*)(vr + (32 << 12));
        bf16x8 vb0 = *(const bf16x8*)(vr + 16);
        bf16x8 vb1 = *(const bf16x8*)(vr + 16 + (32 << 12));
        O0 = mfma32(pf0, va0, O0);
        O1 = mfma32(pf0, va1, O1);
        O0 = mfma32(pf1, vb0, O0);
        O1 = mfma32(pf1, vb1, O1);
    }

    // ---- merge: l across h, then O across 4 waves via 2 LDS buffers ----
    float lsum2 = ls + __shfl_xor(ls, 32);
    if (h == 0) l_s[w][l32] = lsum2;
    float* buf = Obuf[w & 1];
    if (w < 2) {
        #pragma unroll
        for (int r = 0; r < 16; ++r) {
            int qrow = (r & 3) + ((r >> 2) << 3) + (h << 2);
            buf[qrow * 68 + l32]      = O0[r];
            buf[qrow * 68 + 32 + l32] = O1[r];
        }
    }
    __syncthreads();
    if (w >= 2) {
        #pragma unroll
        for (int r = 0; r < 16; ++r) {
            int qrow = (r & 3) + ((r >> 2) << 3) + (h << 2);
            buf[qrow * 68 + l32]      += O0[r];
            buf[qrow * 68 + 32 + l32] += O1[r];
        }
    }
    __syncthreads();
    {
        int q  = tid >> 3;
        int d0 = (tid & 7) << 3;
        float inv = 1.f / (l_s[0][q] + l_s[1][q] + l_s[2][q] + l_s[3][q]);
        const float* b0 = Obuf[0] + q * 68 + d0;
        const float* b1 = Obuf[1] + q * 68 + d0;
        float* dst = xg2 + (((size_t)(bt << 12) + qbase + q) << 6) + d0;
        #pragma unroll
        for (int i = 0; i < 8; ++i) dst[i] = (b0[i] + b1[i]) * inv;
    }
}

// ---------------- k_hyper: fused hypernetwork contraction ------------------
__global__ __launch_bounds__(256, 2) void k_hyper(const float* __restrict__ x,
                                                  const float* __restrict__ xg2,
                                                  const unsigned short* __restrict__ ne_bf,
                                                  const unsigned short* __restrict__ wpT,
                                                  const float* __restrict__ bias_ws,
                                                  float* __restrict__ out) {
    __shared__ float smem[13056];          // 52.2 KB: xg (4x3104) then red (4x3264)
    const int t    = threadIdx.x;
    const int w    = t >> 6;
    const int lane = t & 63;
    const int l16  = lane & 15;
    const int quad = lane >> 4;
    const int n0   = (blockIdx.x >> 1) << 4;
    const int oh   = blockIdx.x & 1;       // o-half

    float* xg_s = smem + w * 3104;
    const float* src = (w < 2) ? x : xg2;
    const int i0 = (w & 1) << 5;
    for (int it = 0; it < 48; ++it) {
        int j  = (it << 6) + lane;         // 0..3071
        int kk = j & 31;
        int btnl = j >> 5;                 // 0..95
        int bt = btnl % 6;
        int nl = btnl / 6;
        xg_s[kk * 97 + btnl] =
            src[(((size_t)(bt << 12) + n0 + nl) << 6) + i0 + kk];
    }
    __syncthreads();

    const unsigned short* nb = ne_bf + ((n0 + l16) << 6) + (quad << 3);
    bf16x8 a0 = *(const bf16x8*)(nb);
    bf16x8 a1 = *(const bf16x8*)(nb + 32);

    float oac[2][4][6];
    #pragma unroll
    for (int oc = 0; oc < 2; ++oc)
        #pragma unroll
        for (int r = 0; r < 4; ++r)
            #pragma unroll
            for (int bt = 0; bt < 6; ++bt) oac[oc][r][bt] = 0.f;

    const int ki_base = w << 5;
    #pragma unroll 2
    for (int kk = 0; kk < 32; ++kk) {
        const int ki = ki_base + kk;
        float g[4][6];
        #pragma unroll
        for (int r = 0; r < 4; ++r) {
            const float* gp = xg_s + kk * 97 + ((quad << 2) + r) * 6;
            #pragma unroll
            for (int bt = 0; bt < 6; ++bt) g[r][bt] = gp[bt];
        }
        #pragma unroll
        for (int oc = 0; oc < 2; ++oc) {
            const unsigned short* bp =
                wpT + (((ki << 6) + ((oh * 2 + oc) << 4) + l16) << 6) + (quad << 3);
            bf16x8 b0 = *(const bf16x8*)(bp);
            bf16x8 b1 = *(const bf16x8*)(bp + 32);
            f32x4 wf = mfma16(a0, b0, f32x4{0.f, 0.f, 0.f, 0.f});
            wf = mfma16(a1, b1, wf);
            #pragma unroll
            for (int r = 0; r < 4; ++r)
                #pragma unroll
                for (int bt = 0; bt < 6; ++bt)
                    oac[oc][r][bt] += wf[r] * g[r][bt];
        }
    }

    __syncthreads();                        // xg_s dead; smem becomes red
    #pragma unroll
    for (int oc = 0; oc < 2; ++oc)
        #pragma unroll
        for (int r = 0; r < 4; ++r)
            #pragma unroll
            for (int bt = 0; bt < 6; ++bt)
                smem[w * 3264 + ((quad << 2) + r) * 204 + bt * 34 + (oc << 4) + l16]
                    = oac[oc][r][bt];
    __syncthreads();
    #pragma unroll
    for (int rr = 0; rr < 4; ++rr) {
        int nl = (w << 2) + rr;
        #pragma unroll
        for (int bp2 = 0; bp2 < 3; ++bp2) {
            int bt = bp2 * 2 + (lane >> 5);
            int ol = lane & 31;
            int o  = (oh << 5) + ol;
            int a  = nl * 204 + bt * 34 + ol;
            float v = smem[a] + smem[a + 3264] + smem[a + 6528] + smem[a + 9792]
                    + bias_ws[(bt << 6) + o];
            out[(((size_t)(bt << 12) + n0 + nl) << 6) + o] = v;
        }
    }
}

// ---------------------------------------------------------------------------
extern "C" void kernel_launch(void* const* d_in, const int* in_sizes, int n_in,
                              void* d_out, int out_size, void* d_ws, size_t ws_size,
                              hipStream_t stream) {
    const float* x         = (const float*)d_in[0];
    const float* node_emb  = (const float*)d_in[1];
    const float* time_emb  = (const float*)d_in[2];
    const float* wp        = (const float*)d_in[3];
    const float* bias_pool = (const float*)d_in[4];
    const float* gamma     = (const float*)d_in[5];
    const float* beta      = (const float*)d_in[6];
    float* out = (float*)d_out;

    char* wsb = (char*)d_ws;
    unsigned short* e_bf  = (unsigned short*)(wsb);                  // 3 MB
    unsigned short* eq_bf = (unsigned short*)(wsb + 3145728);        // 3 MB
    unsigned short* xT    = (unsigned short*)(wsb + 6291456);        // 3 MB
    float*          xg2   = (float*)         (wsb + 9437184);        // 6.3 MB
    unsigned short* wpT   = (unsigned short*)(wsb + 15728640);       // 1 MB
    unsigned short* ne_bf = (unsigned short*)(wsb + 16777216);       // 0.5 MB
    float*          biasw = (float*)         (wsb + 17301504);       // 1.5 KB

    k_prep<<<7681, 256, 0, stream>>>(x, node_emb, time_emb, wp, bias_pool,
                                     gamma, beta, e_bf, eq_bf, xT, ne_bf, wpT, biasw);
    k_attn<<<768, 256, 0, stream>>>(e_bf, eq_bf, xT, xg2);
    k_hyper<<<512, 256, 0, stream>>>(x, xg2, ne_bf, wpT, biasw, out);
}